// Round 5
// baseline (344.229 us; speedup 1.0000x reference)
//
#include <hip/hip_runtime.h>

#define W_ 160
#define H_ 128
#define C_ 32
#define D_ 48
#define HW_ (H_*W_)      // 20480
#define TX 16
#define TY 16
#define HPX 18
#define HPY 18
#define NHP (HPX*HPY)    // 324
#define NHPP 336         // padded to 21 MFMA tiles of 16
#define NT 21            // MFMA tiles
#define DST 28           // DL stride in halfs (27 live taps kd*9+sp, +1 pad)

typedef _Float16 h8 __attribute__((ext_vector_type(8)));
typedef float f4 __attribute__((ext_vector_type(4)));

__device__ __forceinline__ void inv4x4(const float* a, float* inv) {
    inv[0]  =  a[5]*a[10]*a[15] - a[5]*a[11]*a[14] - a[9]*a[6]*a[15] + a[9]*a[7]*a[14] + a[13]*a[6]*a[11] - a[13]*a[7]*a[10];
    inv[4]  = -a[4]*a[10]*a[15] + a[4]*a[11]*a[14] + a[8]*a[6]*a[15] - a[8]*a[7]*a[14] - a[12]*a[6]*a[11] + a[12]*a[7]*a[10];
    inv[8]  =  a[4]*a[9]*a[15]  - a[4]*a[11]*a[13] - a[8]*a[5]*a[15] + a[8]*a[7]*a[13] + a[12]*a[5]*a[11] - a[12]*a[7]*a[9];
    inv[12] = -a[4]*a[9]*a[14]  + a[4]*a[10]*a[13] + a[8]*a[5]*a[14] - a[8]*a[6]*a[13] - a[12]*a[5]*a[10] + a[12]*a[6]*a[9];
    inv[1]  = -a[1]*a[10]*a[15] + a[1]*a[11]*a[14] + a[9]*a[2]*a[15] - a[9]*a[3]*a[14] - a[13]*a[2]*a[11] + a[13]*a[3]*a[10];
    inv[5]  =  a[0]*a[10]*a[15] - a[0]*a[11]*a[14] - a[8]*a[2]*a[15] + a[8]*a[3]*a[14] + a[12]*a[2]*a[11] - a[12]*a[3]*a[10];
    inv[9]  = -a[0]*a[9]*a[15]  + a[0]*a[11]*a[13] + a[8]*a[1]*a[15] - a[8]*a[3]*a[13] - a[12]*a[1]*a[11] + a[12]*a[3]*a[9];
    inv[13] =  a[0]*a[9]*a[14]  - a[0]*a[10]*a[13] - a[8]*a[1]*a[14] + a[8]*a[2]*a[13] + a[12]*a[1]*a[10] - a[12]*a[2]*a[9];
    inv[2]  =  a[1]*a[6]*a[15]  - a[1]*a[7]*a[14]  - a[5]*a[2]*a[15] + a[5]*a[3]*a[14] + a[13]*a[2]*a[7]  - a[13]*a[3]*a[6];
    inv[6]  = -a[0]*a[6]*a[15]  + a[0]*a[7]*a[14]  + a[4]*a[2]*a[15] - a[4]*a[3]*a[14] - a[12]*a[2]*a[7]  + a[12]*a[3]*a[6];
    inv[10] =  a[0]*a[5]*a[15]  - a[0]*a[7]*a[13]  - a[4]*a[1]*a[15] + a[4]*a[3]*a[13] + a[12]*a[1]*a[7]  - a[12]*a[3]*a[5];
    inv[14] = -a[0]*a[5]*a[14]  + a[0]*a[6]*a[13]  + a[4]*a[1]*a[14] - a[4]*a[2]*a[13] - a[12]*a[1]*a[6]  + a[12]*a[2]*a[5];
    inv[3]  = -a[1]*a[6]*a[11]  + a[1]*a[7]*a[10]  + a[5]*a[2]*a[11] - a[5]*a[3]*a[10] - a[9]*a[2]*a[7]   + a[9]*a[3]*a[6];
    inv[7]  =  a[0]*a[6]*a[11]  - a[0]*a[7]*a[10]  - a[4]*a[2]*a[11] + a[4]*a[3]*a[10] + a[8]*a[2]*a[7]   - a[8]*a[3]*a[6];
    inv[11] = -a[0]*a[5]*a[11]  + a[0]*a[7]*a[9]   + a[4]*a[1]*a[11] - a[4]*a[3]*a[9]  - a[8]*a[1]*a[7]   + a[8]*a[3]*a[5];
    inv[15] =  a[0]*a[5]*a[10]  - a[0]*a[6]*a[9]   - a[4]*a[1]*a[10] + a[4]*a[2]*a[9]  + a[8]*a[1]*a[6]   - a[8]*a[2]*a[5];
    float det = a[0]*inv[0] + a[1]*inv[4] + a[2]*inv[8] + a[3]*inv[12];
    float id = 1.0f / det;
    for (int i = 0; i < 16; ++i) inv[i] *= id;
}

__device__ __forceinline__ void fuseProj(const float* proj, int i, float* F) {
    const float* A = proj + i*32;   // pair[0]
    const float* R = A + 16;        // pair[1]
    for (int r = 0; r < 3; ++r)
        for (int k = 0; k < 4; ++k)
            F[r*4+k] = R[r*4]*A[k] + R[r*4+1]*A[4+k] + R[r*4+2]*A[8+k];
    for (int k = 0; k < 4; ++k) F[12+k] = A[12+k];
}

// Fused setup: bx<320 -> feature transpose; bx>=320 -> RX planes + M publish.
__global__ __launch_bounds__(256) void kS(const float* __restrict__ f,
                                          const float* __restrict__ proj,
                                          _Float16* __restrict__ ft,
                                          float* __restrict__ RX,
                                          float* __restrict__ M) {
    __shared__ float t[64][33];
    const int bx = blockIdx.x, v = blockIdx.y;
    const int tid = threadIdx.x;
    if (bx < 320) {
        const int p0 = bx * 64;
        const int pl = tid & 63;
        const int cb = (tid >> 6) * 8;
        #pragma unroll
        for (int k = 0; k < 8; ++k)
            t[pl][cb + k] = f[(size_t)(v*C_ + cb + k)*HW_ + p0 + pl];
        __syncthreads();
        const int px = tid >> 2;
        const int c0 = (tid & 3) * 8;
        h8 o;
        #pragma unroll
        for (int k = 0; k < 8; ++k) o[k] = (_Float16)t[px][c0 + k];
        *(h8*)&ft[((size_t)(v*HW_ + p0 + px) << 5) + c0] = o;
    } else {
        if (v >= 4) return;
        float F0[16], Fv[16], inv[16], P[12];
        fuseProj(proj, 0, F0);
        fuseProj(proj, v + 1, Fv);
        inv4x4(F0, inv);
        #pragma unroll
        for (int r = 0; r < 3; ++r)
            #pragma unroll
            for (int c = 0; c < 4; ++c) {
                float acc = 0.f;
                #pragma unroll
                for (int k = 0; k < 4; ++k) acc += Fv[r*4+k]*inv[k*4+c];
                P[r*4+c] = acc;
            }
        const int p = (bx - 320)*256 + tid;
        const float x = (float)(p % W_), y = (float)(p / W_);
        float4 o;
        o.x = P[0]*x + P[1]*y + P[2];
        o.y = P[4]*x + P[5]*y + P[6];
        o.z = P[8]*x + P[9]*y + P[10];
        o.w = 0.f;
        ((float4*)RX)[(size_t)v*HW_ + p] = o;
        if (bx == 320 && tid == 0) {
            float* om = M + v*12;
            om[0]=P[0]; om[1]=P[1]; om[2]=P[2];
            om[3]=P[4]; om[4]=P[5]; om[5]=P[6];
            om[6]=P[8]; om[7]=P[9]; om[8]=P[10];
            om[9]=P[3]; om[10]=P[7]; om[11]=P[11];
        }
    }
}

// Fused main, 2 depths/block: per wave-tile compute variance directly in
// MFMA A-layout (no VT LDS), MFMA per tap-group, spatial shifted sum -> Q.
// Corners gathered once (d0 indices), reused for d1 via exact index compare.
__global__ __launch_bounds__(256, 4) void kA(const _Float16* __restrict__ featH,
                                             const float* __restrict__ RX,
                                             const float* __restrict__ M,
                                             const float* __restrict__ dvals,
                                             const float* __restrict__ regw,
                                             float* __restrict__ Q) {
    __shared__ __align__(16) _Float16 DL0[NHPP*DST];   // 18816 B
    __shared__ __align__(16) _Float16 DL1[NHPP*DST];   // 18816 B

    const int tid = threadIdx.x;
    const int bx = blockIdx.x, by = blockIdx.y;
    const int d0 = blockIdx.z*2, d1 = d0 + 1;
    const int lane = tid & 63;
    const int wv = tid >> 6;
    const int n = lane & 15;       // px-in-tile / output col
    const int grp = lane >> 4;     // channel group (8 ch)
    const float dv0 = dvals[d0], dv1 = dvals[d1];

    // B fragments: col = kd*9 + sp (kd-major), 27 live cols
    h8 bf0, bf1;
    {
        const int kb = grp * 8;
        #pragma unroll
        for (int j = 0; j < 8; ++j) {
            const int ch = kb + j;
            bf0[j] = (_Float16)regw[ch*27 + n];
            bf1[j] = (_Float16)((n < 11) ? regw[ch*27 + 16 + n] : 0.f);
        }
    }

    const h8 hz = {(_Float16)0,(_Float16)0,(_Float16)0,(_Float16)0,
                   (_Float16)0,(_Float16)0,(_Float16)0,(_Float16)0};
    const h8* F = (const h8*)featH;
    const float4* RX4 = (const float4*)RX;
    const f4 fz = {0.f, 0.f, 0.f, 0.f};

    // ---- Fused variance + MFMA per 16-px tile (tile = pass*4 + wave) ----
    #pragma unroll 1
    for (int pass = 0; pass < 6; ++pass) {
        const int tile = pass*4 + wv;
        if (tile >= NT) continue;
        const int px = tile*16 + n;
        h8 var0 = hz, var1 = hz;
        const int hx = px % HPX;
        const int hy = px / HPX;
        const int lx = bx*TX + hx - 1;
        const int ly = by*TY + hy - 1;
        if (px < NHP && lx >= 0 && lx < W_ && ly >= 0 && ly < H_) {
            const int rp = ly*W_ + lx;
            const h8 fr = F[(size_t)rp*4 + grp];
            h8 s0 = fr, q0 = fr*fr, s1 = fr, q1 = fr*fr;
            #pragma unroll
            for (int v = 0; v < 4; ++v) {
                const float4 a = RX4[(size_t)v*HW_ + rp];
                const float tx = M[v*12+9], ty = M[v*12+10], tz = M[v*12+11];
                // depth d0
                const float z0 = a.z*dv0 + tz;
                const float rz0 = 1.0f / z0;
                const float pxf0 = (a.x*dv0 + tx)*rz0;
                const float pyf0 = (a.y*dv0 + ty)*rz0;
                const float fx0 = floorf(pxf0), fy0 = floorf(pyf0);
                const float wxf0 = pxf0 - fx0, wyf0 = pyf0 - fy0;
                const float vxl0 = (fx0 >= 0.f  && fx0 <= 159.f) ? 1.f : 0.f;
                const float vxh0 = (fx0 >= -1.f && fx0 <= 158.f) ? 1.f : 0.f;
                const float vyl0 = (fy0 >= 0.f  && fy0 <= 127.f) ? 1.f : 0.f;
                const float vyh0 = (fy0 >= -1.f && fy0 <= 126.f) ? 1.f : 0.f;
                const int xs0 = (int)fminf(fmaxf(fx0 + 1.f, 0.f), 160.f);
                const int ys0 = (int)fminf(fmaxf(fy0 + 1.f, 0.f), 128.f);
                const int x0 = max(xs0-1, 0), x1 = min(xs0, W_-1);
                const int y0W = max(ys0-1, 0)*W_, y1W = min(ys0, H_-1)*W_;
                const _Float16 w00a = (_Float16)((1.f-wxf0)*vxl0 * (1.f-wyf0)*vyl0);
                const _Float16 w10a = (_Float16)(wxf0*vxh0 * (1.f-wyf0)*vyl0);
                const _Float16 w01a = (_Float16)((1.f-wxf0)*vxl0 * wyf0*vyh0);
                const _Float16 w11a = (_Float16)(wxf0*vxh0 * wyf0*vyh0);
                const h8* Fv = F + (size_t)(v+1)*HW_*4;
                const h8 f00 = Fv[(size_t)(y0W+x0)*4 + grp];
                const h8 f10 = Fv[(size_t)(y0W+x1)*4 + grp];
                const h8 f01 = Fv[(size_t)(y1W+x0)*4 + grp];
                const h8 f11 = Fv[(size_t)(y1W+x1)*4 + grp];
                const h8 g0 = f00*w00a + f10*w10a + f01*w01a + f11*w11a;
                s0 += g0; q0 += g0*g0;
                // depth d1 (reuse corners when indices identical)
                const float z1 = a.z*dv1 + tz;
                const float rz1 = 1.0f / z1;
                const float pxf1 = (a.x*dv1 + tx)*rz1;
                const float pyf1 = (a.y*dv1 + ty)*rz1;
                const float fx1 = floorf(pxf1), fy1 = floorf(pyf1);
                const float wxf1 = pxf1 - fx1, wyf1 = pyf1 - fy1;
                const float vxl1 = (fx1 >= 0.f  && fx1 <= 159.f) ? 1.f : 0.f;
                const float vxh1 = (fx1 >= -1.f && fx1 <= 158.f) ? 1.f : 0.f;
                const float vyl1 = (fy1 >= 0.f  && fy1 <= 127.f) ? 1.f : 0.f;
                const float vyh1 = (fy1 >= -1.f && fy1 <= 126.f) ? 1.f : 0.f;
                const int xs1 = (int)fminf(fmaxf(fx1 + 1.f, 0.f), 160.f);
                const int ys1 = (int)fminf(fmaxf(fy1 + 1.f, 0.f), 128.f);
                const _Float16 w00b = (_Float16)((1.f-wxf1)*vxl1 * (1.f-wyf1)*vyl1);
                const _Float16 w10b = (_Float16)(wxf1*vxh1 * (1.f-wyf1)*vyl1);
                const _Float16 w01b = (_Float16)((1.f-wxf1)*vxl1 * wyf1*vyh1);
                const _Float16 w11b = (_Float16)(wxf1*vxh1 * wyf1*vyh1);
                h8 F00 = f00, F10 = f10, F01 = f01, F11 = f11;
                if ((xs1 != xs0) || (ys1 != ys0)) {
                    const int xa = max(xs1-1, 0), xb = min(xs1, W_-1);
                    const int yaW = max(ys1-1, 0)*W_, ybW = min(ys1, H_-1)*W_;
                    F00 = Fv[(size_t)(yaW+xa)*4 + grp];
                    F10 = Fv[(size_t)(yaW+xb)*4 + grp];
                    F01 = Fv[(size_t)(ybW+xa)*4 + grp];
                    F11 = Fv[(size_t)(ybW+xb)*4 + grp];
                }
                const h8 g1 = F00*w00b + F10*w10b + F01*w01b + F11*w11b;
                s1 += g1; q1 += g1*g1;
            }
            const _Float16 c5 = (_Float16)0.2f;
            const h8 sa = s0 * c5, sb = s1 * c5;
            var0 = q0*c5 - sa*sa;
            var1 = q1*c5 - sb*sb;
        }
        // variance already in MFMA A-layout: lane holds A[px=n][k=grp*8..+8]
        const f4 a0 = __builtin_amdgcn_mfma_f32_16x16x32_f16(var0, bf0, fz, 0, 0, 0);
        const f4 b0 = __builtin_amdgcn_mfma_f32_16x16x32_f16(var0, bf1, fz, 0, 0, 0);
        const f4 a1 = __builtin_amdgcn_mfma_f32_16x16x32_f16(var1, bf0, fz, 0, 0, 0);
        const f4 b1 = __builtin_amdgcn_mfma_f32_16x16x32_f16(var1, bf1, fz, 0, 0, 0);
        const int rbase = tile*16 + grp*4;
        #pragma unroll
        for (int r = 0; r < 4; ++r) {
            _Float16* dr0 = &DL0[(rbase + r)*DST];
            _Float16* dr1 = &DL1[(rbase + r)*DST];
            dr0[n] = (_Float16)a0[r];
            dr1[n] = (_Float16)a1[r];
            if (n < 11) {
                dr0[16 + n] = (_Float16)b0[r];
                dr1[16 + n] = (_Float16)b1[r];
            }
        }
    }
    __syncthreads();

    // ---- 27-term spatial shifted sum -> Q[kd][d][p], both depths ----
    {
        const int x = tid & 15;
        const int y = tid >> 4;
        float c00 = 0.f, c01 = 0.f, c02 = 0.f;
        float c10 = 0.f, c11 = 0.f, c12 = 0.f;
        #pragma unroll
        for (int jy = 0; jy < 3; ++jy) {
            #pragma unroll
            for (int jx = 0; jx < 3; ++jx) {
                const int hp = (y + jy)*HPX + (x + jx);
                const int sp = jy*3 + jx;
                const _Float16* dr0 = &DL0[hp*DST];
                const _Float16* dr1 = &DL1[hp*DST];
                c00 += (float)dr0[sp];
                c01 += (float)dr0[9 + sp];
                c02 += (float)dr0[18 + sp];
                c10 += (float)dr1[sp];
                c11 += (float)dr1[9 + sp];
                c12 += (float)dr1[18 + sp];
            }
        }
        const int p = (by*TY + y)*W_ + bx*TX + x;
        Q[(size_t)(0*D_ + d0)*HW_ + p] = c00;
        Q[(size_t)(1*D_ + d0)*HW_ + p] = c01;
        Q[(size_t)(2*D_ + d0)*HW_ + p] = c02;
        Q[(size_t)(0*D_ + d1)*HW_ + p] = c10;
        Q[(size_t)(1*D_ + d1)*HW_ + p] = c11;
        Q[(size_t)(2*D_ + d1)*HW_ + p] = c12;
    }
}

// Finalize: combine depth taps, softmax over D, depth + confidence
__global__ __launch_bounds__(128) void kB(const float* __restrict__ Q,
                                          const float* __restrict__ dvals,
                                          float* __restrict__ out) {
    const int p = blockIdx.x*128 + threadIdx.x;
    const float* Q0 = Q;
    const float* Q1 = Q + (size_t)D_*HW_;
    const float* Q2 = Q + (size_t)2*D_*HW_;
    float pr[D_];
    #pragma unroll
    for (int d = 0; d < D_; ++d) {
        float c = Q1[d*HW_ + p];
        if (d > 0)     c += Q0[(d-1)*HW_ + p];
        if (d < D_-1)  c += Q2[(d+1)*HW_ + p];
        pr[d] = c;
    }
    float m = pr[0];
    #pragma unroll
    for (int d = 1; d < D_; ++d) m = fmaxf(m, pr[d]);
    float s = 0.f;
    #pragma unroll
    for (int d = 0; d < D_; ++d) { const float e = __expf(pr[d] - m); pr[d] = e; s += e; }
    const float is = 1.f / s;
    float depth = 0.f, fidx = 0.f;
    #pragma unroll
    for (int d = 0; d < D_; ++d) {
        const float pp = pr[d] * is;
        pr[d] = pp;
        depth += pp * dvals[d];
        fidx  += pp * (float)d;
    }
    int di = (int)fidx;
    di = di < 0 ? 0 : (di > D_-1 ? D_-1 : di);
    float conf = 0.f;
    #pragma unroll
    for (int d = 0; d < D_; ++d)
        conf += ((d >= di-1) && (d <= di+2)) ? pr[d] : 0.f;
    out[p] = depth;
    out[HW_ + p] = conf;
}

extern "C" void kernel_launch(void* const* d_in, const int* in_sizes, int n_in,
                              void* d_out, int out_size, void* d_ws, size_t ws_size,
                              hipStream_t stream) {
    const float* features = (const float*)d_in[0];
    const float* proj     = (const float*)d_in[1];
    const float* dvals    = (const float*)d_in[2];
    const float* regw     = (const float*)d_in[3];
    float* out = (float*)d_out;

    _Float16* featH = (_Float16*)d_ws;                       // 5*HW*32 f16 = 6.55 MB
    float* RX = (float*)(featH + (size_t)5*HW_*C_);          // 4*HW*4 f32 = 5.24 MB
    float* M  = RX + (size_t)4*HW_*4;                        // 48 floats (+pad)
    float* Q  = M + 64;                                      // 3*48*HW f32 = 11.8 MB

    kS<<<dim3(400, 5), 256, 0, stream>>>(features, proj, featH, RX, M);
    kA<<<dim3(W_/TX, H_/TY, D_/2), 256, 0, stream>>>(featH, RX, M, dvals, regw, Q);
    kB<<<HW_/128, 128, 0, stream>>>(Q, dvals, out);
}

// Round 6
// 163.992 us; speedup vs baseline: 2.0991x; 2.0991x over previous
//
#include <hip/hip_runtime.h>

#define W_ 160
#define H_ 128
#define C_ 32
#define D_ 48
#define HW_ (H_*W_)      // 20480
#define TX 16
#define TY 16
#define HPX 18
#define HPY 18
#define NHP (HPX*HPY)    // 324
#define NHPP 336         // padded to 21 MFMA tiles of 16
#define NT 21            // MFMA tiles
#define DST 28           // DL stride in halfs (27 live taps kd*9+sp, +1 pad)

typedef _Float16 h8 __attribute__((ext_vector_type(8)));
typedef float f4 __attribute__((ext_vector_type(4)));

__device__ __forceinline__ void inv4x4(const float* a, float* inv) {
    inv[0]  =  a[5]*a[10]*a[15] - a[5]*a[11]*a[14] - a[9]*a[6]*a[15] + a[9]*a[7]*a[14] + a[13]*a[6]*a[11] - a[13]*a[7]*a[10];
    inv[4]  = -a[4]*a[10]*a[15] + a[4]*a[11]*a[14] + a[8]*a[6]*a[15] - a[8]*a[7]*a[14] - a[12]*a[6]*a[11] + a[12]*a[7]*a[10];
    inv[8]  =  a[4]*a[9]*a[15]  - a[4]*a[11]*a[13] - a[8]*a[5]*a[15] + a[8]*a[7]*a[13] + a[12]*a[5]*a[11] - a[12]*a[7]*a[9];
    inv[12] = -a[4]*a[9]*a[14]  + a[4]*a[10]*a[13] + a[8]*a[5]*a[14] - a[8]*a[6]*a[13] - a[12]*a[5]*a[10] + a[12]*a[6]*a[9];
    inv[1]  = -a[1]*a[10]*a[15] + a[1]*a[11]*a[14] + a[9]*a[2]*a[15] - a[9]*a[3]*a[14] - a[13]*a[2]*a[11] + a[13]*a[3]*a[10];
    inv[5]  =  a[0]*a[10]*a[15] - a[0]*a[11]*a[14] - a[8]*a[2]*a[15] + a[8]*a[3]*a[14] + a[12]*a[2]*a[11] - a[12]*a[3]*a[10];
    inv[9]  = -a[0]*a[9]*a[15]  + a[0]*a[11]*a[13] + a[8]*a[1]*a[15] - a[8]*a[3]*a[13] - a[12]*a[1]*a[11] + a[12]*a[3]*a[9];
    inv[13] =  a[0]*a[9]*a[14]  - a[0]*a[10]*a[13] - a[8]*a[1]*a[14] + a[8]*a[2]*a[13] + a[12]*a[1]*a[10] - a[12]*a[2]*a[9];
    inv[2]  =  a[1]*a[6]*a[15]  - a[1]*a[7]*a[14]  - a[5]*a[2]*a[15] + a[5]*a[3]*a[14] + a[13]*a[2]*a[7]  - a[13]*a[3]*a[6];
    inv[6]  = -a[0]*a[6]*a[15]  + a[0]*a[7]*a[14]  + a[4]*a[2]*a[15] - a[4]*a[3]*a[14] - a[12]*a[2]*a[7]  + a[12]*a[3]*a[6];
    inv[10] =  a[0]*a[5]*a[15]  - a[0]*a[7]*a[13]  - a[4]*a[1]*a[15] + a[4]*a[3]*a[13] + a[12]*a[1]*a[7]  - a[12]*a[3]*a[5];
    inv[14] = -a[0]*a[5]*a[14]  + a[0]*a[6]*a[13]  + a[4]*a[1]*a[14] - a[4]*a[2]*a[13] - a[12]*a[1]*a[6]  + a[12]*a[2]*a[5];
    inv[3]  = -a[1]*a[6]*a[11]  + a[1]*a[7]*a[10]  + a[5]*a[2]*a[11] - a[5]*a[3]*a[10] - a[9]*a[2]*a[7]   + a[9]*a[3]*a[6];
    inv[7]  =  a[0]*a[6]*a[11]  - a[0]*a[7]*a[10]  - a[4]*a[2]*a[11] + a[4]*a[3]*a[10] + a[8]*a[2]*a[7]   - a[8]*a[3]*a[6];
    inv[11] = -a[0]*a[5]*a[11]  + a[0]*a[7]*a[9]   + a[4]*a[1]*a[11] - a[4]*a[3]*a[9]  - a[8]*a[1]*a[7]   + a[8]*a[3]*a[5];
    inv[15] =  a[0]*a[5]*a[10]  - a[0]*a[6]*a[9]   - a[4]*a[1]*a[10] + a[4]*a[2]*a[9]  + a[8]*a[1]*a[6]   - a[8]*a[2]*a[5];
    float det = a[0]*inv[0] + a[1]*inv[4] + a[2]*inv[8] + a[3]*inv[12];
    float id = 1.0f / det;
    for (int i = 0; i < 16; ++i) inv[i] *= id;
}

__device__ __forceinline__ void fuseProj(const float* proj, int i, float* F) {
    const float* A = proj + i*32;   // pair[0]
    const float* R = A + 16;        // pair[1]
    for (int r = 0; r < 3; ++r)
        for (int k = 0; k < 4; ++k)
            F[r*4+k] = R[r*4]*A[k] + R[r*4+1]*A[4+k] + R[r*4+2]*A[8+k];
    for (int k = 0; k < 4; ++k) F[12+k] = A[12+k];
}

// Fused setup: bx<320 -> feature transpose; bx>=320 -> RX planes + M publish.
__global__ __launch_bounds__(256) void kS(const float* __restrict__ f,
                                          const float* __restrict__ proj,
                                          _Float16* __restrict__ ft,
                                          float* __restrict__ RX,
                                          float* __restrict__ M) {
    __shared__ float t[64][33];
    const int bx = blockIdx.x, v = blockIdx.y;
    const int tid = threadIdx.x;
    if (bx < 320) {
        const int p0 = bx * 64;
        const int pl = tid & 63;
        const int cb = (tid >> 6) * 8;
        #pragma unroll
        for (int k = 0; k < 8; ++k)
            t[pl][cb + k] = f[(size_t)(v*C_ + cb + k)*HW_ + p0 + pl];
        __syncthreads();
        const int px = tid >> 2;
        const int c0 = (tid & 3) * 8;
        h8 o;
        #pragma unroll
        for (int k = 0; k < 8; ++k) o[k] = (_Float16)t[px][c0 + k];
        *(h8*)&ft[((size_t)(v*HW_ + p0 + px) << 5) + c0] = o;
    } else {
        if (v >= 4) return;
        float F0[16], Fv[16], inv[16], P[12];
        fuseProj(proj, 0, F0);
        fuseProj(proj, v + 1, Fv);
        inv4x4(F0, inv);
        #pragma unroll
        for (int r = 0; r < 3; ++r)
            #pragma unroll
            for (int c = 0; c < 4; ++c) {
                float acc = 0.f;
                #pragma unroll
                for (int k = 0; k < 4; ++k) acc += Fv[r*4+k]*inv[k*4+c];
                P[r*4+c] = acc;
            }
        const int p = (bx - 320)*256 + tid;
        const float x = (float)(p % W_), y = (float)(p / W_);
        float4 o;
        o.x = P[0]*x + P[1]*y + P[2];
        o.y = P[4]*x + P[5]*y + P[6];
        o.z = P[8]*x + P[9]*y + P[10];
        o.w = 0.f;
        ((float4*)RX)[(size_t)v*HW_ + p] = o;
        if (bx == 320 && tid == 0) {
            float* om = M + v*12;
            om[0]=P[0]; om[1]=P[1]; om[2]=P[2];
            om[3]=P[4]; om[4]=P[5]; om[5]=P[6];
            om[6]=P[8]; om[7]=P[9]; om[8]=P[10];
            om[9]=P[3]; om[10]=P[7]; om[11]=P[11];
        }
    }
}

// Fused main, 2 depths/block: variance in MFMA A-layout (registers), corners
// gathered ONCE per (px,view) and shared by both depths (weights for d1 taken
// relative to d0's floor -- displacement between adjacent depths ~1e-3 px).
__global__ __launch_bounds__(256) void kA(const _Float16* __restrict__ featH,
                                          const float* __restrict__ RX,
                                          const float* __restrict__ M,
                                          const float* __restrict__ dvals,
                                          const float* __restrict__ regw,
                                          float* __restrict__ Q) {
    __shared__ __align__(16) _Float16 DL0[NHPP*DST];   // 18816 B
    __shared__ __align__(16) _Float16 DL1[NHPP*DST];   // 18816 B

    const int tid = threadIdx.x;
    const int bx = blockIdx.x, by = blockIdx.y;
    const int d0 = blockIdx.z*2, d1 = d0 + 1;
    const int lane = tid & 63;
    const int wv = tid >> 6;
    const int n = lane & 15;       // px-in-tile / output col
    const int grp = lane >> 4;     // channel group (8 ch)
    const float dv0 = dvals[d0], dv1 = dvals[d1];

    // B fragments: col = kd*9 + sp (kd-major), 27 live cols
    h8 bf0, bf1;
    {
        const int kb = grp * 8;
        #pragma unroll
        for (int j = 0; j < 8; ++j) {
            const int ch = kb + j;
            bf0[j] = (_Float16)regw[ch*27 + n];
            bf1[j] = (_Float16)((n < 11) ? regw[ch*27 + 16 + n] : 0.f);
        }
    }

    const h8 hz = {(_Float16)0,(_Float16)0,(_Float16)0,(_Float16)0,
                   (_Float16)0,(_Float16)0,(_Float16)0,(_Float16)0};
    const h8* F = (const h8*)featH;
    const float4* RX4 = (const float4*)RX;
    const f4 fz = {0.f, 0.f, 0.f, 0.f};
    const _Float16 one = (_Float16)1.f;

    #pragma unroll 1
    for (int pass = 0; pass < 6; ++pass) {
        const int tile = pass*4 + wv;
        if (tile >= NT) continue;
        const int px = tile*16 + n;
        h8 var0 = hz, var1 = hz;
        const int hx = px % HPX;
        const int hy = px / HPX;
        const int lx = bx*TX + hx - 1;
        const int ly = by*TY + hy - 1;
        if (px < NHP && lx >= 0 && lx < W_ && ly >= 0 && ly < H_) {
            const int rp = ly*W_ + lx;
            const h8 fr = F[(size_t)rp*4 + grp];
            h8 s0 = fr, q0 = fr*fr, s1 = fr, q1 = fr*fr;
            #pragma unroll 1
            for (int v = 0; v < 4; ++v) {
                const float4 a = RX4[(size_t)v*HW_ + rp];
                const float tx = M[v*12+9], ty = M[v*12+10], tz = M[v*12+11];
                // depth d0: exact projection (clamped to keep weights finite)
                const float z0 = a.z*dv0 + tz;
                const float rz0 = 1.0f / z0;
                const float pxf0 = fminf(fmaxf((a.x*dv0 + tx)*rz0, -8.f), 168.f);
                const float pyf0 = fminf(fmaxf((a.y*dv0 + ty)*rz0, -8.f), 136.f);
                const float fx = floorf(pxf0), fy = floorf(pyf0);
                const bool vxl = (fx >= 0.f  && fx <= 159.f);
                const bool vxh = (fx >= -1.f && fx <= 158.f);
                const bool vyl = (fy >= 0.f  && fy <= 127.f);
                const bool vyh = (fy >= -1.f && fy <= 126.f);
                const int xs = (int)fminf(fmaxf(fx + 1.f, 0.f), 160.f);
                const int ys = (int)fminf(fmaxf(fy + 1.f, 0.f), 128.f);
                const int x0 = max(xs-1, 0), x1 = min(xs, W_-1);
                const int y0W = max(ys-1, 0)*W_, y1W = min(ys, H_-1)*W_;
                const h8* Fv = F + (size_t)(v+1)*HW_*4;
                h8 f00 = Fv[(size_t)(y0W+x0)*4 + grp];
                h8 f10 = Fv[(size_t)(y0W+x1)*4 + grp];
                h8 f01 = Fv[(size_t)(y1W+x0)*4 + grp];
                h8 f11 = Fv[(size_t)(y1W+x1)*4 + grp];
                // validity folded onto corners (shared by both depths)
                if (!(vxl && vyl)) f00 = hz;
                if (!(vxh && vyl)) f10 = hz;
                if (!(vxl && vyh)) f01 = hz;
                if (!(vxh && vyh)) f11 = hz;
                // d0 bilinear
                const _Float16 wx1a = (_Float16)(pxf0 - fx);
                const _Float16 wy1a = (_Float16)(pyf0 - fy);
                const _Float16 wx0a = one - wx1a, wy0a = one - wy1a;
                const h8 g0 = f00*(wx0a*wy0a) + f10*(wx1a*wy0a)
                            + f01*(wx0a*wy1a) + f11*(wx1a*wy1a);
                s0 += g0; q0 += g0*g0;
                // d1 bilinear: weights relative to d0's floor, same corners
                const float z1 = a.z*dv1 + tz;
                const float rz1 = 1.0f / z1;
                const float pxf1 = fminf(fmaxf((a.x*dv1 + tx)*rz1, -8.f), 168.f);
                const float pyf1 = fminf(fmaxf((a.y*dv1 + ty)*rz1, -8.f), 136.f);
                const _Float16 wx1b = (_Float16)(pxf1 - fx);
                const _Float16 wy1b = (_Float16)(pyf1 - fy);
                const _Float16 wx0b = one - wx1b, wy0b = one - wy1b;
                const h8 g1 = f00*(wx0b*wy0b) + f10*(wx1b*wy0b)
                            + f01*(wx0b*wy1b) + f11*(wx1b*wy1b);
                s1 += g1; q1 += g1*g1;
            }
            const _Float16 c5 = (_Float16)0.2f;
            const h8 sa = s0 * c5, sb = s1 * c5;
            var0 = q0*c5 - sa*sa;
            var1 = q1*c5 - sb*sb;
        }
        // variance already in MFMA A-layout: lane holds A[px=n][k=grp*8..+8]
        const f4 a0 = __builtin_amdgcn_mfma_f32_16x16x32_f16(var0, bf0, fz, 0, 0, 0);
        const f4 b0 = __builtin_amdgcn_mfma_f32_16x16x32_f16(var0, bf1, fz, 0, 0, 0);
        const f4 a1 = __builtin_amdgcn_mfma_f32_16x16x32_f16(var1, bf0, fz, 0, 0, 0);
        const f4 b1 = __builtin_amdgcn_mfma_f32_16x16x32_f16(var1, bf1, fz, 0, 0, 0);
        const int rbase = tile*16 + grp*4;
        #pragma unroll
        for (int r = 0; r < 4; ++r) {
            _Float16* dr0 = &DL0[(rbase + r)*DST];
            _Float16* dr1 = &DL1[(rbase + r)*DST];
            dr0[n] = (_Float16)a0[r];
            dr1[n] = (_Float16)a1[r];
            if (n < 11) {
                dr0[16 + n] = (_Float16)b0[r];
                dr1[16 + n] = (_Float16)b1[r];
            }
        }
    }
    __syncthreads();

    // ---- 27-term spatial shifted sum -> Q[kd][d][p], both depths ----
    {
        const int x = tid & 15;
        const int y = tid >> 4;
        float c00 = 0.f, c01 = 0.f, c02 = 0.f;
        float c10 = 0.f, c11 = 0.f, c12 = 0.f;
        #pragma unroll
        for (int jy = 0; jy < 3; ++jy) {
            #pragma unroll
            for (int jx = 0; jx < 3; ++jx) {
                const int hp = (y + jy)*HPX + (x + jx);
                const int sp = jy*3 + jx;
                const _Float16* dr0 = &DL0[hp*DST];
                const _Float16* dr1 = &DL1[hp*DST];
                c00 += (float)dr0[sp];
                c01 += (float)dr0[9 + sp];
                c02 += (float)dr0[18 + sp];
                c10 += (float)dr1[sp];
                c11 += (float)dr1[9 + sp];
                c12 += (float)dr1[18 + sp];
            }
        }
        const int p = (by*TY + y)*W_ + bx*TX + x;
        Q[(size_t)(0*D_ + d0)*HW_ + p] = c00;
        Q[(size_t)(1*D_ + d0)*HW_ + p] = c01;
        Q[(size_t)(2*D_ + d0)*HW_ + p] = c02;
        Q[(size_t)(0*D_ + d1)*HW_ + p] = c10;
        Q[(size_t)(1*D_ + d1)*HW_ + p] = c11;
        Q[(size_t)(2*D_ + d1)*HW_ + p] = c12;
    }
}

// Finalize: combine depth taps, softmax over D, depth + confidence
__global__ __launch_bounds__(128) void kB(const float* __restrict__ Q,
                                          const float* __restrict__ dvals,
                                          float* __restrict__ out) {
    const int p = blockIdx.x*128 + threadIdx.x;
    const float* Q0 = Q;
    const float* Q1 = Q + (size_t)D_*HW_;
    const float* Q2 = Q + (size_t)2*D_*HW_;
    float pr[D_];
    #pragma unroll
    for (int d = 0; d < D_; ++d) {
        float c = Q1[d*HW_ + p];
        if (d > 0)     c += Q0[(d-1)*HW_ + p];
        if (d < D_-1)  c += Q2[(d+1)*HW_ + p];
        pr[d] = c;
    }
    float m = pr[0];
    #pragma unroll
    for (int d = 1; d < D_; ++d) m = fmaxf(m, pr[d]);
    float s = 0.f;
    #pragma unroll
    for (int d = 0; d < D_; ++d) { const float e = __expf(pr[d] - m); pr[d] = e; s += e; }
    const float is = 1.f / s;
    float depth = 0.f, fidx = 0.f;
    #pragma unroll
    for (int d = 0; d < D_; ++d) {
        const float pp = pr[d] * is;
        pr[d] = pp;
        depth += pp * dvals[d];
        fidx  += pp * (float)d;
    }
    int di = (int)fidx;
    di = di < 0 ? 0 : (di > D_-1 ? D_-1 : di);
    float conf = 0.f;
    #pragma unroll
    for (int d = 0; d < D_; ++d)
        conf += ((d >= di-1) && (d <= di+2)) ? pr[d] : 0.f;
    out[p] = depth;
    out[HW_ + p] = conf;
}

extern "C" void kernel_launch(void* const* d_in, const int* in_sizes, int n_in,
                              void* d_out, int out_size, void* d_ws, size_t ws_size,
                              hipStream_t stream) {
    const float* features = (const float*)d_in[0];
    const float* proj     = (const float*)d_in[1];
    const float* dvals    = (const float*)d_in[2];
    const float* regw     = (const float*)d_in[3];
    float* out = (float*)d_out;

    _Float16* featH = (_Float16*)d_ws;                       // 5*HW*32 f16 = 6.55 MB
    float* RX = (float*)(featH + (size_t)5*HW_*C_);          // 4*HW*4 f32 = 5.24 MB
    float* M  = RX + (size_t)4*HW_*4;                        // 48 floats (+pad)
    float* Q  = M + 64;                                      // 3*48*HW f32 = 11.8 MB

    kS<<<dim3(400, 5), 256, 0, stream>>>(features, proj, featH, RX, M);
    kA<<<dim3(W_/TX, H_/TY, D_/2), 256, 0, stream>>>(featH, RX, M, dvals, regw, Q);
    kB<<<HW_/128, 128, 0, stream>>>(Q, dvals, out);
}

// Round 7
// 149.382 us; speedup vs baseline: 2.3044x; 1.0978x over previous
//
#include <hip/hip_runtime.h>

#define W_ 160
#define H_ 128
#define C_ 32
#define D_ 48
#define HW_ (H_*W_)      // 20480
#define TX 16
#define TY 16
#define HPX 18
#define HPY 18
#define NHP (HPX*HPY)    // 324
#define NHPP 336         // padded to 21 MFMA tiles of 16
#define NT 21            // MFMA tiles
#define DST 28           // DL stride in halfs (27 live taps kd*9+sp, +1 pad)

typedef _Float16 h8 __attribute__((ext_vector_type(8)));
typedef __fp16 fp16x2 __attribute__((ext_vector_type(2)));
typedef float f4 __attribute__((ext_vector_type(4)));

__device__ __forceinline__ _Float16 u2h(unsigned int u) {
    union { unsigned short s; _Float16 h; } x; x.s = (unsigned short)u; return x.h;
}
__device__ __forceinline__ unsigned int pkh2(float a, float b) {
    union { fp16x2 h; unsigned int u; } x;
    x.h = __builtin_amdgcn_cvt_pkrtz(a, b);
    return x.u;
}

__device__ __forceinline__ void inv4x4(const float* a, float* inv) {
    inv[0]  =  a[5]*a[10]*a[15] - a[5]*a[11]*a[14] - a[9]*a[6]*a[15] + a[9]*a[7]*a[14] + a[13]*a[6]*a[11] - a[13]*a[7]*a[10];
    inv[4]  = -a[4]*a[10]*a[15] + a[4]*a[11]*a[14] + a[8]*a[6]*a[15] - a[8]*a[7]*a[14] - a[12]*a[6]*a[11] + a[12]*a[7]*a[10];
    inv[8]  =  a[4]*a[9]*a[15]  - a[4]*a[11]*a[13] - a[8]*a[5]*a[15] + a[8]*a[7]*a[13] + a[12]*a[5]*a[11] - a[12]*a[7]*a[9];
    inv[12] = -a[4]*a[9]*a[14]  + a[4]*a[10]*a[13] + a[8]*a[5]*a[14] - a[8]*a[6]*a[13] - a[12]*a[5]*a[10] + a[12]*a[6]*a[9];
    inv[1]  = -a[1]*a[10]*a[15] + a[1]*a[11]*a[14] + a[9]*a[2]*a[15] - a[9]*a[3]*a[14] - a[13]*a[2]*a[11] + a[13]*a[3]*a[10];
    inv[5]  =  a[0]*a[10]*a[15] - a[0]*a[11]*a[14] - a[8]*a[2]*a[15] + a[8]*a[3]*a[14] + a[12]*a[2]*a[11] - a[12]*a[3]*a[10];
    inv[9]  = -a[0]*a[9]*a[15]  + a[0]*a[11]*a[13] + a[8]*a[1]*a[15] - a[8]*a[3]*a[13] - a[12]*a[1]*a[11] + a[12]*a[3]*a[9];
    inv[13] =  a[0]*a[9]*a[14]  - a[0]*a[10]*a[13] - a[8]*a[1]*a[14] + a[8]*a[2]*a[13] + a[12]*a[1]*a[10] - a[12]*a[2]*a[9];
    inv[2]  =  a[1]*a[6]*a[15]  - a[1]*a[7]*a[14]  - a[5]*a[2]*a[15] + a[5]*a[3]*a[14] + a[13]*a[2]*a[7]  - a[13]*a[3]*a[6];
    inv[6]  = -a[0]*a[6]*a[15]  + a[0]*a[7]*a[14]  + a[4]*a[2]*a[15] - a[4]*a[3]*a[14] - a[12]*a[2]*a[7]  + a[12]*a[3]*a[6];
    inv[10] =  a[0]*a[5]*a[15]  - a[0]*a[7]*a[13]  - a[4]*a[1]*a[15] + a[4]*a[3]*a[13] + a[12]*a[1]*a[7]  - a[12]*a[3]*a[5];
    inv[14] = -a[0]*a[5]*a[14]  + a[0]*a[6]*a[13]  + a[4]*a[1]*a[14] - a[4]*a[2]*a[13] - a[12]*a[1]*a[6]  + a[12]*a[2]*a[5];
    inv[3]  = -a[1]*a[6]*a[11]  + a[1]*a[7]*a[10]  + a[5]*a[2]*a[11] - a[5]*a[3]*a[10] - a[9]*a[2]*a[7]   + a[9]*a[3]*a[6];
    inv[7]  =  a[0]*a[6]*a[11]  - a[0]*a[7]*a[10]  - a[4]*a[2]*a[11] + a[4]*a[3]*a[10] + a[8]*a[2]*a[7]   - a[8]*a[3]*a[6];
    inv[11] = -a[0]*a[5]*a[11]  + a[0]*a[7]*a[9]   + a[4]*a[1]*a[11] - a[4]*a[3]*a[9]  - a[8]*a[1]*a[7]   + a[8]*a[3]*a[5];
    inv[15] =  a[0]*a[5]*a[10]  - a[0]*a[6]*a[9]   - a[4]*a[1]*a[10] + a[4]*a[2]*a[9]  + a[8]*a[1]*a[6]   - a[8]*a[2]*a[5];
    float det = a[0]*inv[0] + a[1]*inv[4] + a[2]*inv[8] + a[3]*inv[12];
    float id = 1.0f / det;
    for (int i = 0; i < 16; ++i) inv[i] *= id;
}

__device__ __forceinline__ void fuseProj(const float* proj, int i, float* F) {
    const float* A = proj + i*32;   // pair[0]
    const float* R = A + 16;        // pair[1]
    for (int r = 0; r < 3; ++r)
        for (int k = 0; k < 4; ++k)
            F[r*4+k] = R[r*4]*A[k] + R[r*4+1]*A[4+k] + R[r*4+2]*A[8+k];
    for (int k = 0; k < 4; ++k) F[12+k] = A[12+k];
}

// Fused setup: bx<320 -> feature transpose; bx>=320 -> RX planes + M publish.
__global__ __launch_bounds__(256) void kS(const float* __restrict__ f,
                                          const float* __restrict__ proj,
                                          _Float16* __restrict__ ft,
                                          float* __restrict__ RX,
                                          float* __restrict__ M) {
    __shared__ float t[64][33];
    const int bx = blockIdx.x, v = blockIdx.y;
    const int tid = threadIdx.x;
    if (bx < 320) {
        const int p0 = bx * 64;
        const int pl = tid & 63;
        const int cb = (tid >> 6) * 8;
        #pragma unroll
        for (int k = 0; k < 8; ++k)
            t[pl][cb + k] = f[(size_t)(v*C_ + cb + k)*HW_ + p0 + pl];
        __syncthreads();
        const int px = tid >> 2;
        const int c0 = (tid & 3) * 8;
        h8 o;
        #pragma unroll
        for (int k = 0; k < 8; ++k) o[k] = (_Float16)t[px][c0 + k];
        *(h8*)&ft[((size_t)(v*HW_ + p0 + px) << 5) + c0] = o;
    } else {
        if (v >= 4) return;
        float F0[16], Fv[16], inv[16], P[12];
        fuseProj(proj, 0, F0);
        fuseProj(proj, v + 1, Fv);
        inv4x4(F0, inv);
        #pragma unroll
        for (int r = 0; r < 3; ++r)
            #pragma unroll
            for (int c = 0; c < 4; ++c) {
                float acc = 0.f;
                #pragma unroll
                for (int k = 0; k < 4; ++k) acc += Fv[r*4+k]*inv[k*4+c];
                P[r*4+c] = acc;
            }
        const int p = (bx - 320)*256 + tid;
        const float x = (float)(p % W_), y = (float)(p / W_);
        float4 o;
        o.x = P[0]*x + P[1]*y + P[2];
        o.y = P[4]*x + P[5]*y + P[6];
        o.z = P[8]*x + P[9]*y + P[10];
        o.w = 0.f;
        ((float4*)RX)[(size_t)v*HW_ + p] = o;
        if (bx == 320 && tid == 0) {
            float* om = M + v*12;
            om[0]=P[0]; om[1]=P[1]; om[2]=P[2];
            om[3]=P[4]; om[4]=P[5]; om[5]=P[6];
            om[6]=P[8]; om[7]=P[9]; om[8]=P[10];
            om[9]=P[3]; om[10]=P[7]; om[11]=P[11];
        }
    }
}

// Fused main, 2 depths/block. Wave-role split: lane (n,g) first computes the
// projection for (px=n, view=g) once (masks folded into packed f16 weights),
// then gathers for (px=n, chan-group=g) pulling each view's params via __shfl.
__global__ __launch_bounds__(256) void kA(const _Float16* __restrict__ featH,
                                          const float* __restrict__ RX,
                                          const float* __restrict__ M,
                                          const float* __restrict__ dvals,
                                          const float* __restrict__ regw,
                                          float* __restrict__ Q) {
    __shared__ __align__(16) _Float16 DL0[NHPP*DST];   // 18816 B
    __shared__ __align__(16) _Float16 DL1[NHPP*DST];   // 18816 B

    const int tid = threadIdx.x;
    const int bx = blockIdx.x, by = blockIdx.y;
    const int d0 = blockIdx.z*2, d1 = d0 + 1;
    const int lane = tid & 63;
    const int wv = tid >> 6;
    const int n = lane & 15;       // px-in-tile (both roles)
    const int grp = lane >> 4;     // view (proj role) / channel group (gather role)
    const float dv0 = dvals[d0], dv1 = dvals[d1];
    // translation for this lane's projection view
    const float tx = M[grp*12 + 9], ty = M[grp*12 + 10], tz = M[grp*12 + 11];

    // B fragments: col = kd*9 + sp (kd-major), 27 live cols
    h8 bf0, bf1;
    {
        const int kb = grp * 8;
        #pragma unroll
        for (int j = 0; j < 8; ++j) {
            const int ch = kb + j;
            bf0[j] = (_Float16)regw[ch*27 + n];
            bf1[j] = (_Float16)((n < 11) ? regw[ch*27 + 16 + n] : 0.f);
        }
    }

    const h8 hz = {(_Float16)0,(_Float16)0,(_Float16)0,(_Float16)0,
                   (_Float16)0,(_Float16)0,(_Float16)0,(_Float16)0};
    const h8* F = (const h8*)featH;
    const float4* RX4 = (const float4*)RX;
    const f4 fz = {0.f, 0.f, 0.f, 0.f};

    #pragma unroll 1
    for (int pass = 0; pass < 6; ++pass) {
        const int tile = pass*4 + wv;          // wave-uniform
        if (tile >= NT) continue;
        const int px = tile*16 + n;
        const int hx = px % HPX;
        const int hy = px / HPX;
        const int lx = bx*TX + hx - 1;
        const int ly = by*TY + hy - 1;
        const bool pok = (px < NHP) && (lx >= 0) && (lx < W_) && (ly >= 0) && (ly < H_);
        const int rp = pok ? (ly*W_ + lx) : 0;

        // ---- projection role: (px, view=grp), both depths ----
        unsigned pidx, pwax, pway, pwbx, pwby;
        {
            const float4 a = RX4[(size_t)grp*HW_ + rp];
            const float z0 = a.z*dv0 + tz;
            const float rz0 = 1.0f / z0;
            const float pxf0 = fminf(fmaxf((a.x*dv0 + tx)*rz0, -8.f), 168.f);
            const float pyf0 = fminf(fmaxf((a.y*dv0 + ty)*rz0, -8.f), 136.f);
            const float fx = floorf(pxf0), fy = floorf(pyf0);
            const float mxl = (fx >= 0.f  && fx <= 159.f) ? 1.f : 0.f;
            const float mxh = (fx >= -1.f && fx <= 158.f) ? 1.f : 0.f;
            const float myl = (fy >= 0.f  && fy <= 127.f) ? 1.f : 0.f;
            const float myh = (fy >= -1.f && fy <= 126.f) ? 1.f : 0.f;
            const int xs = (int)fminf(fmaxf(fx + 1.f, 0.f), 160.f);
            const int ys = (int)fminf(fmaxf(fy + 1.f, 0.f), 128.f);
            const int x0 = max(xs-1, 0), x1 = min(xs, W_-1);
            const int y0 = max(ys-1, 0), y1 = min(ys, H_-1);
            pidx = (unsigned)x0 | ((unsigned)x1 << 8)
                 | ((unsigned)y0 << 16) | ((unsigned)y1 << 24);
            const float wx1a = pxf0 - fx, wy1a = pyf0 - fy;
            pwax = pkh2((1.f - wx1a)*mxl, wx1a*mxh);
            pway = pkh2((1.f - wy1a)*myl, wy1a*myh);
            const float z1 = a.z*dv1 + tz;
            const float rz1 = 1.0f / z1;
            const float pxf1 = fminf(fmaxf((a.x*dv1 + tx)*rz1, -8.f), 168.f);
            const float pyf1 = fminf(fmaxf((a.y*dv1 + ty)*rz1, -8.f), 136.f);
            const float wx1b = pxf1 - fx, wy1b = pyf1 - fy;
            pwbx = pkh2((1.f - wx1b)*mxl, wx1b*mxh);
            pwby = pkh2((1.f - wy1b)*myl, wy1b*myh);
            if (!pok) { pwax = 0u; pway = 0u; pwbx = 0u; pwby = 0u; }
        }

        // ---- gather role: (px, chan-group=grp) ----
        h8 var0 = hz, var1 = hz;
        h8 s0 = hz, q0 = hz, s1 = hz, q1 = hz;
        if (pok) {
            const h8 fr = F[(size_t)rp*4 + grp];
            s0 = fr; q0 = fr*fr; s1 = fr; q1 = q0;
        }
        #pragma unroll 1
        for (int v = 0; v < 4; ++v) {
            const int src = v*16 + n;
            const unsigned idxv = (unsigned)__shfl((int)pidx, src, 64);
            const unsigned ax   = (unsigned)__shfl((int)pwax, src, 64);
            const unsigned ay   = (unsigned)__shfl((int)pway, src, 64);
            const unsigned bxw  = (unsigned)__shfl((int)pwbx, src, 64);
            const unsigned byw  = (unsigned)__shfl((int)pwby, src, 64);
            if (pok) {
                const int x0 = idxv & 0xff, x1 = (idxv >> 8) & 0xff;
                const int y0W = ((idxv >> 16) & 0xff) * W_;
                const int y1W = (idxv >> 24) * W_;
                const h8* Fv = F + (size_t)(v+1)*HW_*4;
                const h8 f00 = Fv[(size_t)(y0W+x0)*4 + grp];
                const h8 f10 = Fv[(size_t)(y0W+x1)*4 + grp];
                const h8 f01 = Fv[(size_t)(y1W+x0)*4 + grp];
                const h8 f11 = Fv[(size_t)(y1W+x1)*4 + grp];
                const _Float16 wx0a = u2h(ax), wx1a = u2h(ax >> 16);
                const _Float16 wy0a = u2h(ay), wy1a = u2h(ay >> 16);
                const h8 g0 = f00*(wx0a*wy0a) + f10*(wx1a*wy0a)
                            + f01*(wx0a*wy1a) + f11*(wx1a*wy1a);
                s0 += g0; q0 += g0*g0;
                const _Float16 wx0b = u2h(bxw), wx1b = u2h(bxw >> 16);
                const _Float16 wy0b = u2h(byw), wy1b = u2h(byw >> 16);
                const h8 g1 = f00*(wx0b*wy0b) + f10*(wx1b*wy0b)
                            + f01*(wx0b*wy1b) + f11*(wx1b*wy1b);
                s1 += g1; q1 += g1*g1;
            }
        }
        if (pok) {
            const _Float16 c5 = (_Float16)0.2f;
            const h8 sa = s0 * c5, sb = s1 * c5;
            var0 = q0*c5 - sa*sa;
            var1 = q1*c5 - sb*sb;
        }
        // variance already in MFMA A-layout: lane holds A[px=n][k=grp*8..+8]
        const f4 a0 = __builtin_amdgcn_mfma_f32_16x16x32_f16(var0, bf0, fz, 0, 0, 0);
        const f4 b0 = __builtin_amdgcn_mfma_f32_16x16x32_f16(var0, bf1, fz, 0, 0, 0);
        const f4 a1 = __builtin_amdgcn_mfma_f32_16x16x32_f16(var1, bf0, fz, 0, 0, 0);
        const f4 b1 = __builtin_amdgcn_mfma_f32_16x16x32_f16(var1, bf1, fz, 0, 0, 0);
        const int rbase = tile*16 + grp*4;
        #pragma unroll
        for (int r = 0; r < 4; ++r) {
            _Float16* dr0 = &DL0[(rbase + r)*DST];
            _Float16* dr1 = &DL1[(rbase + r)*DST];
            dr0[n] = (_Float16)a0[r];
            dr1[n] = (_Float16)a1[r];
            if (n < 11) {
                dr0[16 + n] = (_Float16)b0[r];
                dr1[16 + n] = (_Float16)b1[r];
            }
        }
    }
    __syncthreads();

    // ---- 27-term spatial shifted sum -> Q[kd][d][p], both depths ----
    {
        const int x = tid & 15;
        const int y = tid >> 4;
        float c00 = 0.f, c01 = 0.f, c02 = 0.f;
        float c10 = 0.f, c11 = 0.f, c12 = 0.f;
        #pragma unroll
        for (int jy = 0; jy < 3; ++jy) {
            #pragma unroll
            for (int jx = 0; jx < 3; ++jx) {
                const int hp = (y + jy)*HPX + (x + jx);
                const int sp = jy*3 + jx;
                const _Float16* dr0 = &DL0[hp*DST];
                const _Float16* dr1 = &DL1[hp*DST];
                c00 += (float)dr0[sp];
                c01 += (float)dr0[9 + sp];
                c02 += (float)dr0[18 + sp];
                c10 += (float)dr1[sp];
                c11 += (float)dr1[9 + sp];
                c12 += (float)dr1[18 + sp];
            }
        }
        const int p = (by*TY + y)*W_ + bx*TX + x;
        Q[(size_t)(0*D_ + d0)*HW_ + p] = c00;
        Q[(size_t)(1*D_ + d0)*HW_ + p] = c01;
        Q[(size_t)(2*D_ + d0)*HW_ + p] = c02;
        Q[(size_t)(0*D_ + d1)*HW_ + p] = c10;
        Q[(size_t)(1*D_ + d1)*HW_ + p] = c11;
        Q[(size_t)(2*D_ + d1)*HW_ + p] = c12;
    }
}

// Finalize: combine depth taps, softmax over D, depth + confidence
__global__ __launch_bounds__(64) void kB(const float* __restrict__ Q,
                                         const float* __restrict__ dvals,
                                         float* __restrict__ out) {
    const int p = blockIdx.x*64 + threadIdx.x;
    const float* Q0 = Q;
    const float* Q1 = Q + (size_t)D_*HW_;
    const float* Q2 = Q + (size_t)2*D_*HW_;
    float pr[D_];
    #pragma unroll
    for (int d = 0; d < D_; ++d) {
        float c = Q1[d*HW_ + p];
        if (d > 0)     c += Q0[(d-1)*HW_ + p];
        if (d < D_-1)  c += Q2[(d+1)*HW_ + p];
        pr[d] = c;
    }
    float m = pr[0];
    #pragma unroll
    for (int d = 1; d < D_; ++d) m = fmaxf(m, pr[d]);
    float s = 0.f;
    #pragma unroll
    for (int d = 0; d < D_; ++d) { const float e = __expf(pr[d] - m); pr[d] = e; s += e; }
    const float is = 1.f / s;
    float depth = 0.f, fidx = 0.f;
    #pragma unroll
    for (int d = 0; d < D_; ++d) {
        const float pp = pr[d] * is;
        pr[d] = pp;
        depth += pp * dvals[d];
        fidx  += pp * (float)d;
    }
    int di = (int)fidx;
    di = di < 0 ? 0 : (di > D_-1 ? D_-1 : di);
    float conf = 0.f;
    #pragma unroll
    for (int d = 0; d < D_; ++d)
        conf += ((d >= di-1) && (d <= di+2)) ? pr[d] : 0.f;
    out[p] = depth;
    out[HW_ + p] = conf;
}

extern "C" void kernel_launch(void* const* d_in, const int* in_sizes, int n_in,
                              void* d_out, int out_size, void* d_ws, size_t ws_size,
                              hipStream_t stream) {
    const float* features = (const float*)d_in[0];
    const float* proj     = (const float*)d_in[1];
    const float* dvals    = (const float*)d_in[2];
    const float* regw     = (const float*)d_in[3];
    float* out = (float*)d_out;

    _Float16* featH = (_Float16*)d_ws;                       // 5*HW*32 f16 = 6.55 MB
    float* RX = (float*)(featH + (size_t)5*HW_*C_);          // 4*HW*4 f32 = 5.24 MB
    float* M  = RX + (size_t)4*HW_*4;                        // 48 floats (+pad)
    float* Q  = M + 64;                                      // 3*48*HW f32 = 11.8 MB

    kS<<<dim3(400, 5), 256, 0, stream>>>(features, proj, featH, RX, M);
    kA<<<dim3(W_/TX, H_/TY, D_/2), 256, 0, stream>>>(featH, RX, M, dvals, regw, Q);
    kB<<<HW_/64, 64, 0, stream>>>(Q, dvals, out);
}